// Round 5
// baseline (261.219 us; speedup 1.0000x reference)
//
#include <hip/hip_runtime.h>
#include <hip/hip_bf16.h>

#define DM 1024
#define SEQ 2048
#define NBATCH 4

using f32x4 = __attribute__((ext_vector_type(4))) float;
using s16x8 = __attribute__((ext_vector_type(8))) short;   // 8 bf16 in 4 VGPRs
using u16x4 = __attribute__((ext_vector_type(4))) unsigned short;
using u16x8 = __attribute__((ext_vector_type(8))) unsigned short;

__device__ __forceinline__ unsigned short f2bf(float f) {
  union { float f; unsigned u; } v; v.f = f;
  return (unsigned short)((v.u + 0x7fffu + ((v.u >> 16) & 1u)) >> 16);  // RNE
}

// async global->LDS, 16B per lane. Dest wave-uniform + lane*16 (linear);
// source per-lane (pre-swizzled).
__device__ __forceinline__ void gll16(const unsigned short* g, unsigned short* l) {
  __builtin_amdgcn_global_load_lds((const __attribute__((address_space(1))) void*)g,
                                   (__attribute__((address_space(3))) void*)l,
                                   16, 0, 0);
}

// ---------------- fused prep: x->bf16 cast  +  W transpose/cast ----------------
__global__ void prep_k(const float* __restrict__ X,
                       const float* __restrict__ Wq, const float* __restrict__ Wk,
                       const float* __restrict__ Wv,
                       unsigned short* __restrict__ XB, unsigned short* __restrict__ WT) {
  __shared__ float t[32][33];
  const int b = blockIdx.x;
  if (b < 4096) {
    const int i = b * 256 + threadIdx.x;
    const f32x4* p = (const f32x4*)X;
    f32x4 a = p[2 * i], c = p[2 * i + 1];
    u16x8 o;
#pragma unroll
    for (int q = 0; q < 4; q++) { o[q] = f2bf(a[q]); o[4 + q] = f2bf(c[q]); }
    *(u16x8*)(XB + (size_t)i * 8) = o;
  } else {
    const int r2 = b - 4096;
    const int seg = r2 >> 10;
    const int rem = r2 & 1023;
    const int k0 = (rem >> 5) * 32, n0 = (rem & 31) * 32;
    const float* W = (seg == 0) ? Wq : (seg == 1) ? Wk : Wv;
    unsigned short* out = WT + (size_t)seg * DM * DM;
    const int tr = threadIdx.x >> 5, tc = threadIdx.x & 31;
#pragma unroll
    for (int p = 0; p < 4; p++) {
      int r = tr + p * 8;
      t[r][tc] = W[(size_t)(k0 + r) * DM + n0 + tc];
    }
    __syncthreads();
#pragma unroll
    for (int p = 0; p < 4; p++) {
      int r = tr + p * 8;
      out[(size_t)(n0 + r) * DM + k0 + tc] = f2bf(t[tc][r]);
    }
  }
}

// =====================================================================
// S-gemm (Q·K^T) — m201-faithful 256^2 8-phase template.
// 512 threads = 8 waves (2M x 4N), per-wave C = 128x64 (acc[8][4]).
// BK=64 split in two 32-col K-halves; LDS = 2 buf x (A 32KB + B 32KB)
// = 128KB, each K-half a contiguous 16KB block (gll-linear dest).
// Swizzle (proven 0-conflict family): 64B rows, 2 rows per 128B line;
// phys chunk c of line L holds row-parity c>>2, k-chunk (c&3)^(L&3);
// staged via pre-swizzled global source.
// Per tile: 4 phases (ks x i-half): {4-8 ds_read_b128; 2 gll16;
// [vmcnt(8) at ph2/ph4]; barrier; lgkm(0); setprio(1); 16 MFMA;
// setprio(0); barrier}.  Stage ledger: KH1(t+1) in ph1/ph2, KH0(t+2)
// in ph3/ph4; prologue tile0 + KH0(1), vmcnt(4); tail vmcnt 8->4->0.
// Grid 256 = 32 Mtiles x 8 Ntiles = EXACTLY 1 block/CU, 1 round.
// Epilogue: softmax stats per 256-wide tile (8 tiles x 4 wn partials),
// P' = exp(s-m[tile]) stored direct (per-row 128B spans merge in L2).
// =====================================================================
__global__ __launch_bounds__(512, 2) void sgemm256_k(
    const unsigned short* __restrict__ Qb,   // [4*2048][1024]
    const unsigned short* __restrict__ Kb,   // [4*2048][1024]
    unsigned short* __restrict__ P,          // [4][2048][2048]
    float* __restrict__ sm,                  // [4*2048][8]
    float* __restrict__ sv) {                // [4*2048][32] (8 tiles x 4 wn)
  __shared__ unsigned short lbuf[65536];     // A: [2buf][2ks][8K shorts] | B same @+32768
  __shared__ float fred[1024];               // row-max exchange [4 wn][256 rows]

  const int tid = threadIdx.x;
  const int w = tid >> 6, l = tid & 63;
  const int ll = l & 15, qd = l >> 4;
  const int wm = w >> 2, wn = w & 3;         // 2M x 4N waves

  const int bid = blockIdx.x;
  const int xcd = bid & 7, slot = bid >> 3;  // 32 slots per XCD
  const int bz = xcd >> 1;
  const int mh = xcd & 1;
  const int nloc = slot & 7, mloc = slot >> 3;
  const int tileM = (mh * 4 + mloc) * 256, tileN = nloc * 256;
  const int nT = nloc;

  // staging: lane l -> line l>>3, chunk l&7 of an 8-line (16-row) span.
  // src row = span + seg*2 + (ch>>2); k-chunk = (ch&3)^(seg&3).
  const int seg = l >> 3, ch = l & 7;
  const int rowo = seg * 2 + (ch >> 2);
  const int kc = (ch & 3) ^ (seg & 3);
  const unsigned short* gA0 = Qb + (size_t)(bz * SEQ + tileM + w * 16 + rowo) * DM + kc * 8;
  const unsigned short* gB0 = Kb + (size_t)(bz * SEQ + tileN + w * 16 + rowo) * DM + kc * 8;

#define STG_A(bsel, t_, ks_) do {                                              \
    unsigned short* d_ = lbuf + (bsel) * 16384 + (ks_) * 8192 + w * 512;       \
    const unsigned short* s_ = gA0 + (t_) * 64 + (ks_) * 32;                   \
    gll16(s_, d_); gll16(s_ + 128 * DM, d_ + 4096); } while (0)
#define STG_B(bsel, t_, ks_) do {                                              \
    unsigned short* d_ = lbuf + 32768 + (bsel) * 16384 + (ks_) * 8192 + w * 512; \
    const unsigned short* s_ = gB0 + (t_) * 64 + (ks_) * 32;                   \
    gll16(s_, d_); gll16(s_ + 128 * DM, d_ + 4096); } while (0)

  // fragment read offsets (shorts) within a 16KB K-half block:
  // row R, k-chunk qd -> line R>>1, chunk (R&1)*4 + (qd^((R>>1)&3)); +16 rows = +512.
  const int Ra = wm * 128 + ll;
  const int aoff0 = (Ra >> 1) * 64 + (((Ra & 1) << 2) + (qd ^ ((Ra >> 1) & 3))) * 8;
  const int Rb = wn * 64 + ll;
  const int boff0 = (Rb >> 1) * 64 + (((Rb & 1) << 2) + (qd ^ ((Rb >> 1) & 3))) * 8;

  f32x4 acc[8][4];
#pragma unroll
  for (int i = 0; i < 8; i++)
#pragma unroll
    for (int j = 0; j < 4; j++) acc[i][j] = (f32x4){0.f, 0.f, 0.f, 0.f};
  s16x8 bfr[4];

#define PH(bsel, ks_, ih_, DOSTG, DOVM, VMC) do {                              \
    const int ab_ = (bsel) * 16384 + (ks_) * 8192;                             \
    s16x8 af_[4];                                                              \
    _Pragma("unroll")                                                          \
    for (int i_ = 0; i_ < 4; i_++)                                             \
      af_[i_] = *(const s16x8*)&lbuf[ab_ + aoff0 + ((ih_) * 4 + i_) * 512];    \
    if (!(ih_)) {                                                              \
      _Pragma("unroll")                                                        \
      for (int j_ = 0; j_ < 4; j_++)                                           \
        bfr[j_] = *(const s16x8*)&lbuf[32768 + ab_ + boff0 + j_ * 512];        \
    }                                                                          \
    DOSTG;                                                                     \
    __builtin_amdgcn_sched_barrier(0);                                         \
    if (DOVM) { __builtin_amdgcn_s_waitcnt(VMC);                               \
                __builtin_amdgcn_sched_barrier(0); }                           \
    __builtin_amdgcn_s_barrier();                                              \
    __builtin_amdgcn_s_waitcnt(0xC07F);    /* lgkmcnt(0) */                    \
    __builtin_amdgcn_sched_barrier(0);                                         \
    __builtin_amdgcn_s_setprio(1);                                             \
    _Pragma("unroll")                                                          \
    for (int i_ = 0; i_ < 4; i_++)                                             \
      _Pragma("unroll")                                                        \
      for (int j_ = 0; j_ < 4; j_++)                                           \
        acc[(ih_) * 4 + i_][j_] = __builtin_amdgcn_mfma_f32_16x16x32_bf16(     \
            af_[i_], bfr[j_], acc[(ih_) * 4 + i_][j_], 0, 0, 0);               \
    __builtin_amdgcn_s_setprio(0);                                             \
    __builtin_amdgcn_sched_barrier(0);                                         \
    __builtin_amdgcn_s_barrier();                                              \
    __builtin_amdgcn_sched_barrier(0);                                         \
  } while (0)

  // ---- prologue: tile0 (8 glls) + tile1 KH0 (4 glls); tile0 landed.
  STG_A(0, 0, 0); STG_A(0, 0, 1); STG_B(0, 0, 0); STG_B(0, 0, 1);
  STG_A(1, 1, 0); STG_B(1, 1, 0);
  __builtin_amdgcn_sched_barrier(0);
  __builtin_amdgcn_s_waitcnt(0x0F74);          // vmcnt(4)
  __builtin_amdgcn_sched_barrier(0);
  __builtin_amdgcn_s_barrier();
  __builtin_amdgcn_sched_barrier(0);

#define TILE_STEADY(bsel, t_) do {                                             \
    PH(bsel, 0, 0, STG_A(1 - (bsel), (t_) + 1, 1), 0, 0);                      \
    PH(bsel, 0, 1, STG_B(1 - (bsel), (t_) + 1, 1), 1, 0x0F78);                 \
    PH(bsel, 1, 0, STG_A(bsel, (t_) + 2, 0), 0, 0);                            \
    PH(bsel, 1, 1, STG_B(bsel, (t_) + 2, 0), 1, 0x0F78);                       \
  } while (0)

  for (int I = 0; I < 7; ++I) {                // tiles 0..13 (K=1024, 16 tiles)
    const int t = 2 * I;
    TILE_STEADY(0, t);
    TILE_STEADY(1, t + 1);
  }
  // tile 14 (buf0): stage KH1(15) only; tail vmcnt 8 -> 4
  PH(0, 0, 0, STG_A(1, 15, 1), 0, 0);
  PH(0, 0, 1, STG_B(1, 15, 1), 1, 0x0F78);
  PH(0, 1, 0, (void)0, 0, 0);
  PH(0, 1, 1, (void)0, 1, 0x0F74);
  // tile 15 (buf1): no staging; vmcnt(0) before its KH1 reads
  PH(1, 0, 0, (void)0, 0, 0);
  PH(1, 0, 1, (void)0, 1, 0x0F70);
  PH(1, 1, 0, (void)0, 0, 0);
  PH(1, 1, 1, (void)0, 0, 0);
#undef TILE_STEADY
#undef PH
#undef STG_A
#undef STG_B

  // ---------------- softmax epilogue (256-wide tiles) ----------------
  // C/D: row = wm*128 + i*16 + qd*4 + r ; col = wn*64 + j*16 + ll
  float mt[8][4];
#pragma unroll
  for (int i = 0; i < 8; i++)
#pragma unroll
    for (int r = 0; r < 4; r++) {
#pragma unroll
      for (int j = 0; j < 4; j++) acc[i][j][r] *= 0.03125f;   // 1/sqrt(1024)
      float v = fmaxf(fmaxf(acc[i][0][r], acc[i][1][r]), fmaxf(acc[i][2][r], acc[i][3][r]));
#pragma unroll
      for (int m = 1; m < 16; m <<= 1) v = fmaxf(v, __shfl_xor(v, m, 16));
      mt[i][r] = v;
    }
  if (ll == 0) {
#pragma unroll
    for (int i = 0; i < 8; i++)
#pragma unroll
      for (int r = 0; r < 4; r++)
        fred[wn * 256 + wm * 128 + i * 16 + qd * 4 + r] = mt[i][r];
  }
  __syncthreads();
#pragma unroll
  for (int i = 0; i < 8; i++)
#pragma unroll
    for (int r = 0; r < 4; r++) {
      const int row = wm * 128 + i * 16 + qd * 4 + r;
      mt[i][r] = fmaxf(fmaxf(fred[row], fred[256 + row]),
                       fmaxf(fred[512 + row], fred[768 + row]));
    }
  unsigned short* Pb = P + (size_t)bz * SEQ * SEQ;
#pragma unroll
  for (int i = 0; i < 8; i++)
#pragma unroll
    for (int r = 0; r < 4; r++) {
      const int row = wm * 128 + i * 16 + qd * 4 + r;
      const int rowg = tileM + row;
      float s = 0.f;
#pragma unroll
      for (int j = 0; j < 4; j++) {
        const float e = __expf(acc[i][j][r] - mt[i][r]);
        s += e;
        Pb[(size_t)rowg * SEQ + tileN + wn * 64 + j * 16 + ll] = f2bf(e);
      }
#pragma unroll
      for (int m = 1; m < 16; m <<= 1) s += __shfl_xor(s, m, 16);
      if (ll == 0) {
        const size_t base = (size_t)bz * SEQ + rowg;
        sv[base * 32 + nT * 4 + wn] = s;
        if (wn == 0) sm[base * 8 + nT] = mt[i][r];
      }
    }
}

// ------- bf16 NT GEMM (proven 128^2 two-barrier K-loop): MODE0 QKV, MODE2 PV ----
// MODE 2 (BM=64): telescoped PV over 256-wide S-tiles (8 scales), fused combine.
template <int MODE, int BM, int LDA, int LDB, int KDIM>
__global__ void gemm_nt(const unsigned short* __restrict__ A,
                        const unsigned short* __restrict__ B,
                        void* __restrict__ C0,
                        unsigned short* __restrict__ C1,
                        unsigned short* __restrict__ C2,
                        const float* __restrict__ bq,
                        const float* __restrict__ bk,
                        const float* __restrict__ bv,
                        float* __restrict__ sm,
                        float* __restrict__ sv,
                        const float* __restrict__ Tt) {
  constexpr int ASTEPS = BM / 32;
  constexpr int NJ = (BM == 128) ? 4 : 2;
  constexpr int WNOFF = 16 * NJ;
  __shared__ unsigned short lbuf[(BM + 128) * 64];
  __shared__ float Tl[(MODE == 2) ? 512 : 1];     // MODE2 fused scale table [8][64]

  const int tid = threadIdx.x;
  const int w = tid >> 6;
  const int L = tid & 63;
  const int wm = (BM == 128) ? (w & 1) : 0;
  const int wn = (BM == 128) ? (w >> 1) : w;
  const int qd = L >> 4, ll = L & 15;

  const int bid = blockIdx.x;
  const int xcd = bid & 7, slot = bid >> 3;
  int bz, tileM, tileN;
  if (MODE == 0) {
    const int pm = xcd & 3, pn = xcd >> 2;
    const int nloc = slot % 12, mloc = slot / 12;
    bz = 0; tileM = (pm * 16 + mloc) * 128; tileN = (pn * 12 + nloc) * 128;
  } else {
    bz = xcd >> 1;
    const int mh = xcd & 1;
    const int nloc = slot & 7, mloc = slot >> 3;
    tileM = (mh * 16 + mloc) * 64; tileN = nloc * 128;
  }

  const unsigned short* Ab = A;
  const unsigned short* Bb = B;
  if (MODE == 2) { Ab += (size_t)bz * SEQ * SEQ; Bb += (size_t)bz * DM * SEQ; }

  const int srow = tid >> 3;
  const int pch = tid & 7;
  const int gch = pch ^ (srow & 7);
  const unsigned short* gA = Ab + (size_t)(tileM + srow) * LDA + gch * 8;
  const unsigned short* gB = Bb + (size_t)(tileN + srow) * LDB + gch * 8;
  unsigned short* lA = lbuf;
  unsigned short* lB = lbuf + BM * 64;
  unsigned short* wAp = &lA[srow * 64 + pch * 8];
  unsigned short* wBp = &lB[srow * 64 + pch * 8];

  u16x8 rA[ASTEPS], rB[4];
#define LOADT(kt) do {                                                         \
    const size_t kk_ = (size_t)(kt) * 64;                                      \
    _Pragma("unroll")                                                          \
    for (int i_ = 0; i_ < ASTEPS; i_++)                                        \
      rA[i_] = *(const u16x8*)(gA + (size_t)i_ * 32 * LDA + kk_);              \
    _Pragma("unroll")                                                          \
    for (int i_ = 0; i_ < 4; i_++)                                             \
      rB[i_] = *(const u16x8*)(gB + (size_t)i_ * 32 * LDB + kk_);              \
  } while (0)
#define WRITET() do {                                                          \
    _Pragma("unroll")                                                          \
    for (int i_ = 0; i_ < ASTEPS; i_++) *(u16x8*)(wAp + i_ * 32 * 64) = rA[i_];\
    _Pragma("unroll")                                                          \
    for (int i_ = 0; i_ < 4; i_++)      *(u16x8*)(wBp + i_ * 32 * 64) = rB[i_];\
  } while (0)

  f32x4 acc[4][NJ];
#pragma unroll
  for (int i = 0; i < 4; i++)
#pragma unroll
    for (int j = 0; j < NJ; j++) acc[i][j] = (f32x4){0.f, 0.f, 0.f, 0.f};

  const int sw = L & 7;

  constexpr int NK = KDIM / 64;
  LOADT(0);

  // ---- MODE2 fused softmax-combine (256-wide S-tiles: 8 stats) ----
  if (MODE == 2 && tid < 64) {
    const size_t rbase = (size_t)bz * SEQ + tileM + tid;
    const float* mrow = sm + rbase * 8;
    const float* srow2 = sv + rbase * 32;
    float mv[8];
#pragma unroll
    for (int t = 0; t < 8; t++) mv[t] = mrow[t];
    float M = mv[0];
#pragma unroll
    for (int t = 1; t < 8; t++) M = fmaxf(M, mv[t]);
    float Lsum = 0.f;
#pragma unroll
    for (int t = 0; t < 8; t++)
      Lsum += (srow2[4 * t] + srow2[4 * t + 1] + srow2[4 * t + 2] + srow2[4 * t + 3]) *
              __expf(mv[t] - M);
#pragma unroll
    for (int t = 1; t < 8; t++) Tl[(t - 1) * 64 + tid] = __expf(mv[t - 1] - mv[t]);
    Tl[7 * 64 + tid] = __expf(mv[7] - M) / Lsum;
  }

  WRITET();
  __syncthreads();

  float tTn[4][4];
  if (MODE == 2) {
#pragma unroll
    for (int i = 0; i < 4; i++)
#pragma unroll
      for (int r = 0; r < 4; r++) tTn[i][r] = Tl[i * 16 + qd * 4 + r];  // scale into tile1
  }

  for (int k = 0; k < NK; ++k) {
    if (MODE == 2 && k >= 4 && (k & 3) == 0) {
      // 256-col S-tile boundary t=k/4: rescale, prefetch next scale
#pragma unroll
      for (int i = 0; i < 4; i++)
#pragma unroll
        for (int j = 0; j < NJ; j++)
#pragma unroll
          for (int r = 0; r < 4; r++) acc[i][j][r] *= tTn[i][r];
      const int tn1 = (k >> 2);                 // index t..: 1..7 (7 = final scale)
#pragma unroll
      for (int i = 0; i < 4; i++)
#pragma unroll
        for (int r = 0; r < 4; r++) tTn[i][r] = Tl[tn1 * 64 + i * 16 + qd * 4 + r];
    }

    if (k + 1 < NK) LOADT(k + 1);

#pragma unroll
    for (int s = 0; s < 2; s++) {
      const int pc = ((s * 4 + qd) ^ sw) * 8;
      s16x8 av[4], bv4[NJ];
#pragma unroll
      for (int i = 0; i < 4; i++)
        av[i] = *(const s16x8*)&lA[(wm * 64 + i * 16 + ll) * 64 + pc];
#pragma unroll
      for (int j = 0; j < NJ; j++)
        bv4[j] = *(const s16x8*)&lB[(wn * WNOFF + j * 16 + ll) * 64 + pc];
#pragma unroll
      for (int i = 0; i < 4; i++)
#pragma unroll
        for (int j = 0; j < NJ; j++)
          acc[i][j] = __builtin_amdgcn_mfma_f32_16x16x32_bf16(av[i], bv4[j], acc[i][j], 0, 0, 0);
    }

    if (k + 1 < NK) {
      __builtin_amdgcn_s_waitcnt(0xC07F);       // lgkmcnt(0); vmem in flight
      __builtin_amdgcn_sched_barrier(0);
      __builtin_amdgcn_s_barrier();
      __builtin_amdgcn_sched_barrier(0);
      WRITET();
      __syncthreads();
    }
  }
#undef LOADT
#undef WRITET

  // ---------------- epilogues ----------------
  if (MODE == 0) {
#pragma unroll
    for (int i = 0; i < 4; i++) {
      const int gm0 = tileM + wm * 64 + i * 16 + qd * 4;
#pragma unroll
      for (int j = 0; j < NJ; j++) {
        const int gn = tileN + wn * WNOFF + j * 16 + ll;
        const int seg = gn >> 10;
        const int colin = gn & 1023;
        if (seg == 0) {
          const float bias = bq[colin];
          unsigned short* Q = (unsigned short*)C0;
#pragma unroll
          for (int r = 0; r < 4; r++) Q[(size_t)(gm0 + r) * DM + colin] = f2bf(acc[i][j][r] + bias);
        } else if (seg == 1) {
          const float bias = bk[colin];
#pragma unroll
          for (int r = 0; r < 4; r++) C1[(size_t)(gm0 + r) * DM + colin] = f2bf(acc[i][j][r] + bias);
        } else {                            // V, transposed: Vt[b][d][s]
          const float bias = bv[colin];
          u16x4 pk;
#pragma unroll
          for (int r = 0; r < 4; r++) pk[r] = f2bf(acc[i][j][r] + bias);
          const int b = gm0 >> 11, s0 = gm0 & 2047;
          *(u16x4*)(C2 + ((size_t)((b << 10) + colin)) * SEQ + s0) = pk;
        }
      }
    }
  } else {
    // final scale (tTn holds exp(m7-M)/L), store fp32
    float* O = (float*)C0 + (size_t)bz * SEQ * DM;
#pragma unroll
    for (int i = 0; i < 4; i++) {
      const int gm0 = tileM + i * 16 + qd * 4;
#pragma unroll
      for (int j = 0; j < NJ; j++) {
        const int gn = tileN + wn * WNOFF + j * 16 + ll;
#pragma unroll
        for (int r = 0; r < 4; r++)
          O[(size_t)(gm0 + r) * DM + gn] = acc[i][j][r] * tTn[i][r];
      }
    }
  }
  (void)sm; (void)sv; (void)Tt;
}

// ---------------- launch ----------------
// ws layout (bytes):
//   xb  @ 0         : 16 MB   bf16 x       [8192,1024]
//   wt  @ 16777216  :  6 MB   bf16 W^T     [3072,1024]
//   qb  @ 23068672  : 16 MB   bf16 Q       [8192,1024]
//   kb  @ 39845888  : 16 MB   bf16 K       [8192,1024]
//   vt  @ 56623104  : 16 MB   bf16 V^T     [4][1024][2048]
//   P   @ 73400320  : 32 MB   bf16 P'      [4][2048][2048]
//   ms  @ 106954752 : 256 KB  fp32 stats m [4][2048][8]
//   ss  @ 107479040 : 1 MB    fp32 stats s [4][2048][32]
extern "C" void kernel_launch(void* const* d_in, const int* in_sizes, int n_in,
                              void* d_out, int out_size, void* d_ws, size_t ws_size,
                              hipStream_t stream) {
  (void)in_sizes; (void)n_in; (void)out_size; (void)ws_size;
  const float* x  = (const float*)d_in[0];
  const float* Wq = (const float*)d_in[1];
  const float* bq = (const float*)d_in[2];
  const float* Wk = (const float*)d_in[3];
  const float* bk = (const float*)d_in[4];
  const float* Wv = (const float*)d_in[5];
  const float* bv = (const float*)d_in[6];
  float* out = (float*)d_out;
  char* ws = (char*)d_ws;
  unsigned short* xb = (unsigned short*)(ws + 0);
  unsigned short* wt = (unsigned short*)(ws + 16777216);
  unsigned short* qb = (unsigned short*)(ws + 23068672);
  unsigned short* kb = (unsigned short*)(ws + 39845888);
  unsigned short* vt = (unsigned short*)(ws + 56623104);
  unsigned short* P  = (unsigned short*)(ws + 73400320);
  float*          ms = (float*)(ws + 106954752);
  float*          ss = (float*)(ws + 107479040);

  prep_k<<<7168, 256, 0, stream>>>(x, Wq, Wk, Wv, xb, wt);
  gemm_nt<0, 128, 1024, 1024, 1024><<<1536, 256, 0, stream>>>(
      xb, wt, (void*)qb, kb, vt, bq, bk, bv, nullptr, nullptr, nullptr);
  sgemm256_k<<<256, 512, 0, stream>>>(qb, kb, P, ms, ss);
  gemm_nt<2, 64, 2048, 2048, 2048><<<1024, 256, 0, stream>>>(
      P, vt, (void*)out, nullptr, nullptr, nullptr, nullptr, nullptr, ms, ss, nullptr);
}